// Round 6
// baseline (273405.664 us; speedup 1.0000x reference)
//
#include <hip/hip_runtime.h>

#define T_STEPS 512
#define HID 1024
#define SEQ_BSTRIDE (T_STEPS * HID)

// ===================== persistent kernel, weights-in-VGPR =====================
// LDS (dwords): z[128 k][32 b] @0 (4096); epilogue reuse: part[512 o][4 wv] @0
// (2048); gates gl[512] @4096.  Total 4608 dw = 18432 B.
#define ZROW 32
#define GL_OFF 4096
#define P_LDS 4608

// z LDS swizzle: value z[k][b] stored at col = b ^ SWZ(k), SWZ = (((k>>2)&7)^(k&3))<<2
__device__ __forceinline__ int zswz(int k) { return ((((k >> 2) & 7) ^ (k & 3)) << 2); }

__launch_bounds__(256, 2)
__global__ void lstm_persist(const float* __restrict__ seq,
                             const float* __restrict__ Wh,
                             const float* __restrict__ Wx,
                             const float* __restrict__ Bias,
                             float* __restrict__ Ht,
                             unsigned* __restrict__ bar,
                             float* __restrict__ dout)
{
    __shared__ float lds[P_LDS];
    const int tid   = threadIdx.x;
    const int blk   = blockIdx.x;
    const int layer = blk & 1;
    const int hblk  = blk >> 1;          // rows hblk*4..+3 per gate

    const int kg = tid >> 3;             // 0..31 : k-slice owner
    const int rg = tid & 7;              // rows rg and rg+8
    const int wv = tid >> 6;             // wave id

    // ---- one-time: load this thread's 128 weight floats into registers ----
    float4 wreg[2][16];
    {
        const int h0 = hblk << 2;
        #pragma unroll
        for (int r = 0; r < 2; ++r) {
            const int row = rg + (r << 3);
            const int g = row >> 2, hl = row & 3;
            const float* wh = Wh + (size_t)(((layer * 4 + g) << 10) + h0 + hl) * 1024;
            const float* wx = Wx + (size_t)(((layer * 4 + g) << 10) + h0 + hl) * 1024;
            #pragma unroll
            for (int c = 0; c < 8; ++c)
                wreg[r][c] = *(const float4*)(wh + (c << 7) + (kg << 2));
            #pragma unroll
            for (int c = 0; c < 8; ++c)
                wreg[r][c + 8] = *(const float4*)(wx + (c << 7) + (kg << 2));
        }
    }

    // staging ids
    const int sdv = tid >> 1, sb2 = tid & 1;   // d-major z: 128 d x 2 b-halves
    const int sb  = tid >> 3, sd  = tid & 7;   // b-major x: 32 b x 8 d-groups

    // bias (2 outputs per thread) + activation-thread bias
    const int o1 = tid, o2 = tid + 256;
    const float bo1 = Bias[((layer * 4 + ((o1 >> 5) >> 2)) << 10) + (hblk << 2) + ((o1 >> 5) & 3)];
    const float bo2 = Bias[((layer * 4 + ((o2 >> 5) >> 2)) << 10) + (hblk << 2) + ((o2 >> 5) & 3)];

    const int act_hl = tid >> 5, act_b = tid & 31;
    float c_reg = 0.f;

    const int swzR = (kg & 7) << 2;      // read-side base swizzle (j XORed in per-instr)

    for (int p = 0; p <= T_STEPS; ++p) {
        const int t = layer ? (p - 1) : p;
        if (t >= 0 && t < T_STEPS) {
            const int pIn = t & 1, pOut = pIn ^ 1;
            const float* zh   = Ht + ((pIn * 2 + layer) << 15);   // own h_prev [d][32]
            const float* zx   = Ht + ((pOut * 2) << 15);          // layer-0 h_new (x for l==1)
            const float* xseq = seq + (size_t)t * HID;
            float* hOut = Ht + ((pOut * 2 + layer) << 15);

            float4 pfz[4];
            auto LOADZ = [&](int c) {
                if (c < 8 || layer == 1) {
                    const float* zr = ((c < 8) ? zh + (c << 12)
                                              : zx + ((c - 8) << 12))
                                      + (sdv << 5) + (sb2 << 4);
                    pfz[0] = ((const float4*)zr)[0];
                    pfz[1] = ((const float4*)zr)[1];
                    pfz[2] = ((const float4*)zr)[2];
                    pfz[3] = ((const float4*)zr)[3];
                } else {
                    const float* xr = xseq + (size_t)sb * SEQ_BSTRIDE + ((c - 8) << 7) + (sd << 4);
                    pfz[0] = ((const float4*)xr)[0];
                    pfz[1] = ((const float4*)xr)[1];
                    pfz[2] = ((const float4*)xr)[2];
                    pfz[3] = ((const float4*)xr)[3];
                }
            };
            auto WRITEZ = [&](int c) {
                if (c < 8 || layer == 1) {
                    const int base = sdv << 5;
                    const int sw   = zswz(sdv);
                    #pragma unroll
                    for (int j = 0; j < 4; ++j)
                        *(float4*)&lds[base + (((sb2 << 4) + (j << 2)) ^ sw)] = pfz[j];
                } else {
                    #pragma unroll
                    for (int j = 0; j < 4; ++j) {
                        const float v[4] = {pfz[j].x, pfz[j].y, pfz[j].z, pfz[j].w};
                        #pragma unroll
                        for (int e = 0; e < 4; ++e) {
                            const int dl = (sd << 4) + (j << 2) + e;
                            lds[(dl << 5) + (sb ^ zswz(dl))] = v[e];
                        }
                    }
                }
            };

            float4 a0[8], a1[8];
            #pragma unroll
            for (int q = 0; q < 8; ++q) {
                a0[q] = make_float4(0.f, 0.f, 0.f, 0.f);
                a1[q] = make_float4(0.f, 0.f, 0.f, 0.f);
            }

            LOADZ(0);
            WRITEZ(0);
            __syncthreads();

            #pragma unroll
            for (int c = 0; c < 16; ++c) {
                if (c < 15) LOADZ(c + 1);
                #pragma unroll
                for (int j = 0; j < 4; ++j) {
                    const int krow = ((kg << 2) + j) << 5;
                    const float w0 = (j == 0) ? wreg[0][c].x : (j == 1) ? wreg[0][c].y
                                   : (j == 2) ? wreg[0][c].z : wreg[0][c].w;
                    const float w1 = (j == 0) ? wreg[1][c].x : (j == 1) ? wreg[1][c].y
                                   : (j == 2) ? wreg[1][c].z : wreg[1][c].w;
                    #pragma unroll
                    for (int q = 0; q < 8; ++q) {
                        const float4 z4 = *(const float4*)&lds[krow + (((q << 2) ^ swzR) ^ (j << 2))];
                        a0[q].x = fmaf(w0, z4.x, a0[q].x);
                        a0[q].y = fmaf(w0, z4.y, a0[q].y);
                        a0[q].z = fmaf(w0, z4.z, a0[q].z);
                        a0[q].w = fmaf(w0, z4.w, a0[q].w);
                        a1[q].x = fmaf(w1, z4.x, a1[q].x);
                        a1[q].y = fmaf(w1, z4.y, a1[q].y);
                        a1[q].z = fmaf(w1, z4.z, a1[q].z);
                        a1[q].w = fmaf(w1, z4.w, a1[q].w);
                    }
                }
                __syncthreads();
                if (c < 15) {
                    WRITEZ(c + 1);
                    __syncthreads();
                }
            }

            // ---- reduce over kg&7 within wave (lane bits 3..5) ----
            #pragma unroll
            for (int q = 0; q < 8; ++q) {
                #pragma unroll
                for (int hv = 0; hv < 2; ++hv) {
                    float4 v = hv ? a1[q] : a0[q];
                    v.x += __shfl_xor(v.x, 8);  v.y += __shfl_xor(v.y, 8);
                    v.z += __shfl_xor(v.z, 8);  v.w += __shfl_xor(v.w, 8);
                    v.x += __shfl_xor(v.x, 16); v.y += __shfl_xor(v.y, 16);
                    v.z += __shfl_xor(v.z, 16); v.w += __shfl_xor(v.w, 16);
                    v.x += __shfl_xor(v.x, 32); v.y += __shfl_xor(v.y, 32);
                    v.z += __shfl_xor(v.z, 32); v.w += __shfl_xor(v.w, 32);
                    if (hv) a1[q] = v; else a0[q] = v;
                }
            }

            // ---- cross-wave partials: part[o][wv] at dw o*4+wv ----
            if ((tid & 56) == 0) {
                #pragma unroll
                for (int r = 0; r < 2; ++r) {
                    const int row = rg + (r << 3);
                    #pragma unroll
                    for (int q = 0; q < 8; ++q) {
                        const float4 v = r ? a1[q] : a0[q];
                        const int ob = ((row << 5) + (q << 2)) << 2;
                        lds[ob + 0  + wv] = v.x;
                        lds[ob + 4  + wv] = v.y;
                        lds[ob + 8  + wv] = v.z;
                        lds[ob + 12 + wv] = v.w;
                    }
                }
            }
            __syncthreads();

            // ---- sum 4 wave-partials + bias -> gl ----
            {
                const float4 p1 = *(const float4*)&lds[o1 << 2];
                const float4 p2 = *(const float4*)&lds[o2 << 2];
                const float s1 = p1.x + p1.y + p1.z + p1.w + bo1;
                const float s2 = p2.x + p2.y + p2.z + p2.w + bo2;
                __syncthreads();
                lds[GL_OFF + o1] = s1;
                lds[GL_OFF + o2] = s2;
            }
            __syncthreads();

            // ---- activations + state update; h via agent-scope stores ----
            if (tid < 128) {
                const float gf = lds[GL_OFF + (0 * 4 + act_hl) * 32 + act_b];
                const float gw = lds[GL_OFF + (1 * 4 + act_hl) * 32 + act_b];
                const float gi = lds[GL_OFF + (2 * 4 + act_hl) * 32 + act_b];
                const float go = lds[GL_OFF + (3 * 4 + act_hl) * 32 + act_b];
                const int h    = (hblk << 2) + act_hl;
                const int sidx = (h << 5) + act_b;
                const float sf  = 1.f / (1.f + __expf(-gf));
                const float sw2 = 1.f / (1.f + __expf(-gw));
                const float ti  = tanhf(gi);
                const float so  = 1.f / (1.f + __expf(-go));
                const float c_new = c_reg * sf + sw2 * ti;
                const float h_new = tanhf(c_new) * so;
                c_reg = c_new;
                __hip_atomic_store(&hOut[sidx], h_new, __ATOMIC_RELAXED, __HIP_MEMORY_SCOPE_AGENT);
                if (layer == 1 && t == T_STEPS - 1)
                    dout[act_b * HID + h] = h_new;
            }
            asm volatile("s_waitcnt vmcnt(0)" ::: "memory");
            __syncthreads();
        }

        // ---- lightweight global barrier (arrive-count + monotonic epoch) ----
        if (p < T_STEPS) {
            if (tid == 0) {
                unsigned old = __hip_atomic_fetch_add(&bar[0], 1u, __ATOMIC_RELAXED,
                                                      __HIP_MEMORY_SCOPE_AGENT);
                if (old == 511u) {
                    __hip_atomic_store(&bar[0], 0u, __ATOMIC_RELAXED, __HIP_MEMORY_SCOPE_AGENT);
                    asm volatile("s_waitcnt vmcnt(0)" ::: "memory");
                    __hip_atomic_store(&bar[32], (unsigned)(p + 1), __ATOMIC_RELAXED,
                                       __HIP_MEMORY_SCOPE_AGENT);
                } else {
                    while (__hip_atomic_load(&bar[32], __ATOMIC_RELAXED,
                                             __HIP_MEMORY_SCOPE_AGENT) < (unsigned)(p + 1)) {
                        __builtin_amdgcn_s_sleep(1);
                    }
                }
                __builtin_amdgcn_fence(__ATOMIC_ACQUIRE, "agent");
            }
            __syncthreads();
        }
    }
}

// ===================== fallback: proven round-2 per-step kernel =====================
#define F_WSTR 20
#define F_ZL 5120
#define F_ZSTR 36
#define F_GLB 4608
#define F_LDS 14336

__launch_bounds__(256, 1)
__global__ void lstm_step_fb(const float* __restrict__ seq,
                             const float* __restrict__ Wh,
                             const float* __restrict__ Wx,
                             const float* __restrict__ Bias,
                             float* __restrict__ Ht,
                             float* __restrict__ C,
                             float* __restrict__ dout,
                             int t, int l, int write_out)
{
    __shared__ float lds[F_LDS];
    const int tid = threadIdx.x;
    const int bid = blockIdx.x;

    const int kg   = tid >> 3;
    const int rowg = (tid >> 2) & 1;
    const int bg   = tid & 3;

    const int pIn = t & 1, pOut = pIn ^ 1;
    const float* zh   = Ht + ((pIn * 2 + l) << 15);
    const float* zx_d = Ht + ((pOut * 2) << 15);
    float* hOut = Ht + ((pOut * 2 + l) << 15);
    float* cPtr = C + (l << 15);

    const int srow = tid >> 4;
    const int skv  = tid & 15;
    const int sdv  = tid >> 3;
    const int sb4  = tid & 7;
    const int sb   = tid >> 3;
    const int sd8  = tid & 7;

    const float* whbase = Wh + ((size_t)(((l * 4 + (srow >> 2)) << 10) + (bid << 2) + (srow & 3))) * 1024;
    const float* wxbase = Wx + ((size_t)(((l * 4 + (srow >> 2)) << 10) + (bid << 2) + (srow & 3))) * 1024;

    float4 pfw[4];
    float4 pfz[8];

    auto LOADC = [&](int c) {
        const float* wb = (c < 4) ? (whbase + c * 256) : (wxbase + (c - 4) * 256);
        #pragma unroll
        for (int j = 0; j < 4; ++j)
            pfw[j] = *(const float4*)(wb + j * 64 + skv * 4);
        if (c < 4) {
            const float* zsrc = zh + (c << 8) * 32;
            #pragma unroll
            for (int j = 0; j < 8; ++j)
                pfz[j] = *(const float4*)(zsrc + (j * 32 + sdv) * 32 + sb4 * 4);
        } else if (l == 1) {
            const float* zsrc = zx_d + ((c - 4) << 8) * 32;
            #pragma unroll
            for (int j = 0; j < 8; ++j)
                pfz[j] = *(const float4*)(zsrc + (j * 32 + sdv) * 32 + sb4 * 4);
        } else {
            const float* xs = seq + (size_t)sb * SEQ_BSTRIDE + t * HID + (c - 4) * 256;
            #pragma unroll
            for (int j = 0; j < 8; ++j)
                pfz[j] = *(const float4*)(xs + j * 32 + sd8 * 4);
        }
    };

    auto WRITEC = [&](int c) {
        #pragma unroll
        for (int j = 0; j < 4; ++j) {
            const int kk = j * 64 + skv * 4;
            lds[(kk + 0) * F_WSTR + srow] = pfw[j].x;
            lds[(kk + 1) * F_WSTR + srow] = pfw[j].y;
            lds[(kk + 2) * F_WSTR + srow] = pfw[j].z;
            lds[(kk + 3) * F_WSTR + srow] = pfw[j].w;
        }
        if (c < 4 || l == 1) {
            #pragma unroll
            for (int j = 0; j < 8; ++j)
                *(float4*)&lds[F_ZL + (j * 32 + sdv) * F_ZSTR + sb4 * 4] = pfz[j];
        } else {
            #pragma unroll
            for (int j = 0; j < 8; ++j) {
                const int dd = j * 32 + sd8 * 4;
                lds[F_ZL + (dd + 0) * F_ZSTR + sb] = pfz[j].x;
                lds[F_ZL + (dd + 1) * F_ZSTR + sb] = pfz[j].y;
                lds[F_ZL + (dd + 2) * F_ZSTR + sb] = pfz[j].z;
                lds[F_ZL + (dd + 3) * F_ZSTR + sb] = pfz[j].w;
            }
        }
    };

    float4 acc[8][2];
    #pragma unroll
    for (int r = 0; r < 8; ++r) {
        acc[r][0] = make_float4(0.f, 0.f, 0.f, 0.f);
        acc[r][1] = make_float4(0.f, 0.f, 0.f, 0.f);
    }

    LOADC(0);
    WRITEC(0);
    __syncthreads();

    const int wbase = kg * F_WSTR + rowg * 8;
    const int zbase = F_ZL + kg * F_ZSTR + bg * 8;

    for (int c = 0; c < 8; ++c) {
        if (c < 7) LOADC(c + 1);

        #pragma unroll
        for (int i = 0; i < 8; ++i) {
            const float* wp = &lds[wbase + i * (32 * F_WSTR)];
            const float* zp = &lds[zbase + i * (32 * F_ZSTR)];
            const float4 wa  = *(const float4*)(wp);
            const float4 wb2 = *(const float4*)(wp + 4);
            const float4 za  = *(const float4*)(zp);
            const float4 zb2 = *(const float4*)(zp + 4);
            const float wr[8] = {wa.x, wa.y, wa.z, wa.w, wb2.x, wb2.y, wb2.z, wb2.w};
            #pragma unroll
            for (int r = 0; r < 8; ++r) {
                acc[r][0].x = fmaf(wr[r], za.x,  acc[r][0].x);
                acc[r][0].y = fmaf(wr[r], za.y,  acc[r][0].y);
                acc[r][0].z = fmaf(wr[r], za.z,  acc[r][0].z);
                acc[r][0].w = fmaf(wr[r], za.w,  acc[r][0].w);
                acc[r][1].x = fmaf(wr[r], zb2.x, acc[r][1].x);
                acc[r][1].y = fmaf(wr[r], zb2.y, acc[r][1].y);
                acc[r][1].z = fmaf(wr[r], zb2.z, acc[r][1].z);
                acc[r][1].w = fmaf(wr[r], zb2.w, acc[r][1].w);
            }
        }

        __syncthreads();
        if (c < 7) {
            WRITEC(c + 1);
            __syncthreads();
        }
    }

    #pragma unroll
    for (int r = 0; r < 8; ++r) {
        #pragma unroll
        for (int q = 0; q < 2; ++q) {
            float4 v = acc[r][q];
            v.x += __shfl_xor(v.x, 8);  v.y += __shfl_xor(v.y, 8);
            v.z += __shfl_xor(v.z, 8);  v.w += __shfl_xor(v.w, 8);
            v.x += __shfl_xor(v.x, 16); v.y += __shfl_xor(v.y, 16);
            v.z += __shfl_xor(v.z, 16); v.w += __shfl_xor(v.w, 16);
            v.x += __shfl_xor(v.x, 32); v.y += __shfl_xor(v.y, 32);
            v.z += __shfl_xor(v.z, 32); v.w += __shfl_xor(v.w, 32);
            acc[r][q] = v;
        }
    }

    const int wv = tid >> 6;
    if ((tid & 56) == 0) {
        #pragma unroll
        for (int r = 0; r < 8; ++r) {
            const float vals[8] = {acc[r][0].x, acc[r][0].y, acc[r][0].z, acc[r][0].w,
                                   acc[r][1].x, acc[r][1].y, acc[r][1].z, acc[r][1].w};
            #pragma unroll
            for (int b2 = 0; b2 < 8; ++b2) {
                const int o  = ((rowg * 8 + r) << 5) + bg * 8 + b2;
                const int sw = ((o >> 3) & 3) * 4 + ((o >> 8) & 1) * 16;
                lds[o * 8 + sw + wv] = vals[b2];
            }
        }
    }
    __syncthreads();

    #pragma unroll
    for (int ii = 0; ii < 2; ++ii) {
        const int o  = tid + ii * 256;
        const int sw = ((o >> 3) & 3) * 4 + ((o >> 8) & 1) * 16;
        const float4 pq = *(const float4*)&lds[o * 8 + sw];
        float s = pq.x + pq.y + pq.z + pq.w;
        const int row = o >> 5;
        const int g = row >> 2, hl = row & 3;
        s += Bias[((l * 4 + g) << 10) + (bid << 2) + hl];
        lds[F_GLB + o] = s;
    }
    __syncthreads();

    if (tid < 128) {
        const int hl = tid >> 5, b = tid & 31;
        const float gf = lds[F_GLB + (0 * 4 + hl) * 32 + b];
        const float gw = lds[F_GLB + (1 * 4 + hl) * 32 + b];
        const float gi = lds[F_GLB + (2 * 4 + hl) * 32 + b];
        const float go = lds[F_GLB + (3 * 4 + hl) * 32 + b];
        const int h = (bid << 2) + hl;
        const int sidx = (h << 5) + b;
        const float c_old = cPtr[sidx];
        const float sf = 1.f / (1.f + __expf(-gf));
        const float sw2 = 1.f / (1.f + __expf(-gw));
        const float ti = tanhf(gi);
        const float so = 1.f / (1.f + __expf(-go));
        const float c_new = c_old * sf + sw2 * ti;
        const float h_new = tanhf(c_new) * so;
        cPtr[sidx] = c_new;
        hOut[sidx] = h_new;
        if (write_out) dout[b * HID + h] = h_new;
    }
}

extern "C" void kernel_launch(void* const* d_in, const int* in_sizes, int n_in,
                              void* d_out, int out_size, void* d_ws, size_t ws_size,
                              hipStream_t stream) {
    const float* seq  = (const float*)d_in[0];
    const float* Wh   = (const float*)d_in[1];
    const float* Wx   = (const float*)d_in[2];
    const float* Bias = (const float*)d_in[3];
    float* Ht   = (float*)d_ws;                  // [2 parity][2 layer][1024][32]
    float* C    = Ht + 131072;                   // fallback cell state
    unsigned* bar = (unsigned*)(C + 65536);      // bar[0]=count, bar[32]=epoch
    float* dout = (float*)d_out;

    hipMemsetAsync(d_ws, 0, (size_t)(131072 + 65536) * sizeof(float) + 256, stream);

    void* args[] = {(void*)&seq, (void*)&Wh, (void*)&Wx, (void*)&Bias,
                    (void*)&Ht, (void*)&bar, (void*)&dout};
    hipError_t err = hipLaunchCooperativeKernel((const void*)lstm_persist,
                                                dim3(512), dim3(256), args, 0, stream);
    if (err != hipSuccess) {
        for (int t = 0; t < T_STEPS; ++t) {
            for (int l = 0; l < 2; ++l) {
                const int wo = (t == T_STEPS - 1 && l == 1) ? 1 : 0;
                lstm_step_fb<<<dim3(256), dim3(256), 0, stream>>>(
                    seq, Wh, Wx, Bias, Ht, C, dout, t, l, wo);
            }
        }
    }
}